// Round 1
// baseline (297.983 us; speedup 1.0000x reference)
//
#include <hip/hip_runtime.h>

typedef __attribute__((ext_vector_type(4))) float  f32x4;
typedef __attribute__((ext_vector_type(4))) __bf16 bf16x4;
typedef __attribute__((ext_vector_type(8))) __bf16 bf16x8;

#define MFMA16 __builtin_amdgcn_mfma_f32_16x16x32_bf16
#define TINY_THR 4.8789098e-18f
#define XOUT_N ((size_t)4096 * 64 * 45)

// LDS planes: row-major, 64 bf16 cols (128 B rows), XOR-swizzled to kill the
// 16-way bank conflict on fragment reads (G4: byte ^= (row&7)<<4).
__device__ __forceinline__ int swz_off(int row, int col) {
  return row * 128 + (((col) << 1) ^ ((row & 7) << 4));
}

// MFMA 16x16x32 bf16 A/B fragment: row/col = lane&15,
// k = half*16 + 4*(lane>>4) + j   (halves in reg pairs [0:1],[2:3]).
__device__ __forceinline__ bf16x8 read_frag(const __bf16* p, int row, int col) {
  const char* base = (const char*)p + row * 128;
  const int r7 = (row & 7) << 4;
  bf16x4 a = *(const bf16x4*)(base + (((col) << 1) ^ r7));
  bf16x4 b = *(const bf16x4*)(base + (((col + 16) << 1) ^ r7));
  bf16x8 r;
  r[0] = a[0]; r[1] = a[1]; r[2] = a[2]; r[3] = a[3];
  r[4] = b[0]; r[5] = b[1]; r[6] = b[2]; r[7] = b[3];
  return r;
}

__device__ __forceinline__ void split_bf16(float v, __bf16& h, __bf16& l) {
  h = (__bf16)v;
  l = (__bf16)(v - (float)h);
}

// ---------------------------------------------------------------------------
// Kernel 1: enc[b][t][o] = relu(x[b][t][:] . W_fc1[o][:] + b_fc1[o]),  f32 out
// One block per batch row b. M=64 (t), N=64 (o), K=512, KC=64.
// bf16x3 split GEMM (hi*hi + hi*lo + lo*hi) ~ f32 accuracy.
// ---------------------------------------------------------------------------
__global__ __launch_bounds__(256, 4) void k_encgemm(
    const float* __restrict__ x, const float* __restrict__ Wfc,
    const float* __restrict__ bfc, float* __restrict__ enc) {
  __shared__ __bf16 xs[2][64 * 64];   // [plane][t row][k col]
  __shared__ __bf16 wsm[2][64 * 64];  // [plane][o row][k col]

  const int tid  = threadIdx.x;
  const int lane = tid & 63;
  const int wv   = tid >> 6;   // wave = M-tile
  const int fr   = lane & 15;
  const int q    = lane >> 4;
  const int b    = blockIdx.x;

  const int srow = tid >> 2;         // staging row (t or o)
  const int scol = (tid & 3) << 4;   // staging col base
  const float* xp = x + ((size_t)b * 64 + srow) * 512 + scol;
  const float* wp = Wfc + (size_t)srow * 512 + scol;

  f32x4 acc[4];
  for (int nt = 0; nt < 4; ++nt) acc[nt] = (f32x4){0.f, 0.f, 0.f, 0.f};

  for (int c = 0; c < 8; ++c) {
    for (int i = 0; i < 4; ++i) {
      f32x4 vx = *(const f32x4*)(xp + c * 64 + i * 4);
      f32x4 vw = *(const f32x4*)(wp + c * 64 + i * 4);
      bf16x4 xh, xl, wh, wl;
      for (int j = 0; j < 4; ++j) {
        __bf16 h, l;
        split_bf16(vx[j], h, l); xh[j] = h; xl[j] = l;
        split_bf16(vw[j], h, l); wh[j] = h; wl[j] = l;
      }
      const int off = swz_off(srow, scol + i * 4);
      *(bf16x4*)((char*)xs[0] + off)  = xh;
      *(bf16x4*)((char*)xs[1] + off)  = xl;
      *(bf16x4*)((char*)wsm[0] + off) = wh;
      *(bf16x4*)((char*)wsm[1] + off) = wl;
    }
    __syncthreads();
    const int arow = wv * 16 + fr;
    bf16x8 Ah[2], Al[2];
    for (int kk = 0; kk < 2; ++kk) {
      Ah[kk] = read_frag(xs[0], arow, kk * 32 + q * 4);
      Al[kk] = read_frag(xs[1], arow, kk * 32 + q * 4);
    }
    for (int nt = 0; nt < 4; ++nt) {
      const int brow = nt * 16 + fr;
      for (int kk = 0; kk < 2; ++kk) {
        bf16x8 Bh = read_frag(wsm[0], brow, kk * 32 + q * 4);
        bf16x8 Bl = read_frag(wsm[1], brow, kk * 32 + q * 4);
        acc[nt] = MFMA16(Ah[kk], Bh, acc[nt], 0, 0, 0);
        acc[nt] = MFMA16(Ah[kk], Bl, acc[nt], 0, 0, 0);
        acc[nt] = MFMA16(Al[kk], Bh, acc[nt], 0, 0, 0);
      }
    }
    __syncthreads();
  }
  // epilogue: D row = t = wv*16 + 4q + e, col = o = nt*16 + fr
  for (int nt = 0; nt < 4; ++nt) {
    const int o = nt * 16 + fr;
    const float bb = bfc[o];
    for (int e = 0; e < 4; ++e) {
      const int t = wv * 16 + q * 4 + e;
      float v = acc[nt][e] + bb;
      enc[((size_t)b * 64 + t) * 64 + o] = fmaxf(v, 0.f);
    }
  }
}

// ---------------------------------------------------------------------------
// Kernel 2: fused GRU scan + logits + softmax + eps mix.
// One block per 16 batch rows; 4 waves; wave j owns h-cols [16j,16j+16).
// gi = MFMA(enc_t pairs, W_ih frags), gh = MFMA(h pairs, W_hh frags) -- both
// bf16x3; n-gate gi/gh kept separate for tanh(i_n + r*h_n). h kept f32 in
// regs; logits of step t computed at iter t+1 from the h-pair LDS.
// ---------------------------------------------------------------------------
__global__ __launch_bounds__(256, 1) void k_scan(
    const float* __restrict__ enc, const float* __restrict__ h0g,
    const float* __restrict__ eps, const float* __restrict__ Wih,
    const float* __restrict__ Whh, const float* __restrict__ bih,
    const float* __restrict__ bhh, const float* __restrict__ Wout,
    const float* __restrict__ bout, float* __restrict__ xout,
    float* __restrict__ hout) {
  __shared__ __bf16 wstage[2][192 * 64];  // staging, reused for Wih/Whh/Wout
  __shared__ __bf16 hp[2][16 * 64];       // h pairs   [plane][b][hcol]
  __shared__ __bf16 epd[2][16 * 64];      // enc pairs [plane][b][o]
  __shared__ float  logit_lds[16][48];

  const int tid  = threadIdx.x;
  const int lane = tid & 63;
  const int wv   = tid >> 6;
  const int fr   = lane & 15;
  const int q    = lane >> 4;
  const int bbase = blockIdx.x * 16;
  const int hcol = wv * 16 + fr;

  bf16x8 Fih[3][2][2], Fhh[3][2][2], Fout[2][2];  // [gate-tile][kk][plane]

  // stage + hoist W_ih  (B frag rows: g = (wv + 4*t3)*16 + fr)
  for (int idx = tid; idx < 192 * 64; idx += 256) {
    __bf16 h, l; split_bf16(Wih[idx], h, l);
    const int off = swz_off(idx >> 6, idx & 63);
    *(__bf16*)((char*)wstage[0] + off) = h;
    *(__bf16*)((char*)wstage[1] + off) = l;
  }
  __syncthreads();
  for (int t3 = 0; t3 < 3; ++t3)
    for (int kk = 0; kk < 2; ++kk) {
      const int row = (wv + 4 * t3) * 16 + fr;
      Fih[t3][kk][0] = read_frag(wstage[0], row, kk * 32 + q * 4);
      Fih[t3][kk][1] = read_frag(wstage[1], row, kk * 32 + q * 4);
    }
  __syncthreads();
  for (int idx = tid; idx < 192 * 64; idx += 256) {
    __bf16 h, l; split_bf16(Whh[idx], h, l);
    const int off = swz_off(idx >> 6, idx & 63);
    *(__bf16*)((char*)wstage[0] + off) = h;
    *(__bf16*)((char*)wstage[1] + off) = l;
  }
  __syncthreads();
  for (int t3 = 0; t3 < 3; ++t3)
    for (int kk = 0; kk < 2; ++kk) {
      const int row = (wv + 4 * t3) * 16 + fr;
      Fhh[t3][kk][0] = read_frag(wstage[0], row, kk * 32 + q * 4);
      Fhh[t3][kk][1] = read_frag(wstage[1], row, kk * 32 + q * 4);
    }
  __syncthreads();
  for (int idx = tid; idx < 48 * 64; idx += 256) {
    float v = (idx < 45 * 64) ? Wout[idx] : 0.f;
    __bf16 h, l; split_bf16(v, h, l);
    const int off = swz_off(idx >> 6, idx & 63);
    *(__bf16*)((char*)wstage[0] + off) = h;
    *(__bf16*)((char*)wstage[1] + off) = l;
  }
  __syncthreads();
  for (int kk = 0; kk < 2; ++kk) {  // wv==3 reads stale rows; unused
    const int row = wv * 16 + fr;
    Fout[kk][0] = read_frag(wstage[0], row, kk * 32 + q * 4);
    Fout[kk][1] = read_frag(wstage[1], row, kk * 32 + q * 4);
  }

  // per-thread state
  float hreg[4];
  for (int e = 0; e < 4; ++e) {
    hreg[e] = h0g[(size_t)(bbase + q * 4 + e) * 64 + hcol];
    __bf16 h, l; split_bf16(hreg[e], h, l);
    const int off = swz_off(q * 4 + e, hcol);
    *(__bf16*)((char*)hp[0] + off) = h;
    *(__bf16*)((char*)hp[1] + off) = l;
  }
  const float biasR  = bih[hcol] + bhh[hcol];
  const float biasZ  = bih[64 + hcol] + bhh[64 + hcol];
  const float biasNi = bih[128 + hcol];
  const float biasNh = bhh[128 + hcol];
  const float boutv  = (hcol < 45) ? bout[hcol] : 0.f;

  const int sb = tid >> 4;            // enc staging / softmax batch row
  const int so = (tid & 15) << 2;     // enc staging col
  const float epsv = eps[bbase + sb];

  {  // pre-stage enc t=0
    f32x4 ev = *(const f32x4*)(enc + ((size_t)(bbase + sb) * 64 + 0) * 64 + so);
    bf16x4 h4, l4;
    for (int c2 = 0; c2 < 4; ++c2) { __bf16 h, l; split_bf16(ev[c2], h, l); h4[c2] = h; l4[c2] = l; }
    const int off = swz_off(sb, so);
    *(bf16x4*)((char*)epd[0] + off) = h4;
    *(bf16x4*)((char*)epd[1] + off) = l4;
  }

  for (int t = 0; t <= 64; ++t) {
    __syncthreads();  // bar A: hp/epd/logit_lds reusable
    bf16x8 Ahh[2], Ahl[2];
    for (int kk = 0; kk < 2; ++kk) {
      Ahh[kk] = read_frag(hp[0], fr, kk * 32 + q * 4);
      Ahl[kk] = read_frag(hp[1], fr, kk * 32 + q * 4);
    }
    if (t > 0 && wv < 3) {  // logits for hs[t-1] (current hp)
      f32x4 lacc = (f32x4){0.f, 0.f, 0.f, 0.f};
      for (int kk = 0; kk < 2; ++kk) {
        lacc = MFMA16(Ahh[kk], Fout[kk][0], lacc, 0, 0, 0);
        lacc = MFMA16(Ahh[kk], Fout[kk][1], lacc, 0, 0, 0);
        lacc = MFMA16(Ahl[kk], Fout[kk][0], lacc, 0, 0, 0);
      }
      for (int e = 0; e < 4; ++e)
        logit_lds[q * 4 + e][hcol] = lacc[e] + boutv;
    }
    f32x4 ev;
    if (t < 63)
      ev = *(const f32x4*)(enc + ((size_t)(bbase + sb) * 64 + (t + 1)) * 64 + so);
    float hnew[4] = {0.f, 0.f, 0.f, 0.f};
    if (t < 64) {
      bf16x8 Aeh[2], Ael[2];
      for (int kk = 0; kk < 2; ++kk) {
        Aeh[kk] = read_frag(epd[0], fr, kk * 32 + q * 4);
        Ael[kk] = read_frag(epd[1], fr, kk * 32 + q * 4);
      }
      f32x4 aR = (f32x4){0.f,0.f,0.f,0.f}, aZ = aR, aNi = aR, aNh = aR;
      for (int kk = 0; kk < 2; ++kk) {
        aR  = MFMA16(Aeh[kk], Fih[0][kk][0], aR, 0,0,0);
        aR  = MFMA16(Aeh[kk], Fih[0][kk][1], aR, 0,0,0);
        aR  = MFMA16(Ael[kk], Fih[0][kk][0], aR, 0,0,0);
        aZ  = MFMA16(Aeh[kk], Fih[1][kk][0], aZ, 0,0,0);
        aZ  = MFMA16(Aeh[kk], Fih[1][kk][1], aZ, 0,0,0);
        aZ  = MFMA16(Ael[kk], Fih[1][kk][0], aZ, 0,0,0);
        aNi = MFMA16(Aeh[kk], Fih[2][kk][0], aNi, 0,0,0);
        aNi = MFMA16(Aeh[kk], Fih[2][kk][1], aNi, 0,0,0);
        aNi = MFMA16(Ael[kk], Fih[2][kk][0], aNi, 0,0,0);
        aR  = MFMA16(Ahh[kk], Fhh[0][kk][0], aR, 0,0,0);
        aR  = MFMA16(Ahh[kk], Fhh[0][kk][1], aR, 0,0,0);
        aR  = MFMA16(Ahl[kk], Fhh[0][kk][0], aR, 0,0,0);
        aZ  = MFMA16(Ahh[kk], Fhh[1][kk][0], aZ, 0,0,0);
        aZ  = MFMA16(Ahh[kk], Fhh[1][kk][1], aZ, 0,0,0);
        aZ  = MFMA16(Ahl[kk], Fhh[1][kk][0], aZ, 0,0,0);
        aNh = MFMA16(Ahh[kk], Fhh[2][kk][0], aNh, 0,0,0);
        aNh = MFMA16(Ahh[kk], Fhh[2][kk][1], aNh, 0,0,0);
        aNh = MFMA16(Ahl[kk], Fhh[2][kk][0], aNh, 0,0,0);
      }
      for (int e = 0; e < 4; ++e) {
        const float rr = 1.f / (1.f + __expf(-(aR[e] + biasR)));
        const float zz = 1.f / (1.f + __expf(-(aZ[e] + biasZ)));
        const float npre = aNi[e] + biasNi + rr * (aNh[e] + biasNh);
        const float nn = 2.f / (1.f + __expf(-2.f * npre)) - 1.f;
        const float hv = (1.f - zz) * nn + zz * hreg[e];
        hreg[e] = hv;
        hnew[e] = hv;
        hout[((size_t)(bbase + q * 4 + e) * 64 + t) * 64 + hcol] = hv;
      }
    }
    __syncthreads();  // bar B: logits complete; hp/epd readers done
    if (t < 64) {
      for (int e = 0; e < 4; ++e) {
        __bf16 h, l; split_bf16(hnew[e], h, l);
        const int off = swz_off(q * 4 + e, hcol);
        *(__bf16*)((char*)hp[0] + off) = h;
        *(__bf16*)((char*)hp[1] + off) = l;
      }
      if (t < 63) {
        bf16x4 h4, l4;
        for (int c2 = 0; c2 < 4; ++c2) { __bf16 h, l; split_bf16(ev[c2], h, l); h4[c2] = h; l4[c2] = l; }
        const int off = swz_off(sb, so);
        *(bf16x4*)((char*)epd[0] + off) = h4;
        *(bf16x4*)((char*)epd[1] + off) = l4;
      }
    }
    if (t > 0) {  // softmax + eps mix for time t-1
      const int sub = tid & 15;
      const float e0 = __expf(logit_lds[sb][sub]);
      const float e1 = (sub + 16 < 45) ? __expf(logit_lds[sb][sub + 16]) : 0.f;
      const float e2 = (sub + 32 < 45) ? __expf(logit_lds[sb][sub + 32]) : 0.f;
      float s = e0 + e1 + e2;
      s += __shfl_xor(s, 1, 16);
      s += __shfl_xor(s, 2, 16);
      s += __shfl_xor(s, 4, 16);
      s += __shfl_xor(s, 8, 16);
      if (s <= TINY_THR) s = 1.f;
      const float sc  = (1.f - epsv) / s;
      const float bse = epsv * (1.f / 45.f);
      float* orow = xout + ((size_t)(bbase + sb) * 64 + (t - 1)) * 45;
      orow[sub] = bse + e0 * sc;
      if (sub + 16 < 45) orow[sub + 16] = bse + e1 * sc;
      if (sub + 32 < 45) orow[sub + 32] = bse + e2 * sc;
    }
  }
}

extern "C" void kernel_launch(void* const* d_in, const int* in_sizes, int n_in,
                              void* d_out, int out_size, void* d_ws, size_t ws_size,
                              hipStream_t stream) {
  (void)in_sizes; (void)n_in; (void)out_size; (void)d_ws; (void)ws_size;
  const float* x    = (const float*)d_in[0];
  const float* h0   = (const float*)d_in[1];
  const float* eps  = (const float*)d_in[2];
  const float* Wfc  = (const float*)d_in[3];
  const float* bfc  = (const float*)d_in[4];
  const float* Wih  = (const float*)d_in[5];
  const float* Whh  = (const float*)d_in[6];
  const float* bih  = (const float*)d_in[7];
  const float* bhh  = (const float*)d_in[8];
  const float* Wout = (const float*)d_in[9];
  const float* bout = (const float*)d_in[10];

  float* xout = (float*)d_out;
  float* hout = xout + XOUT_N;
  // enc scratch aliases the h_out region (exactly 4096*64*64 f32); k_scan
  // overwrites enc[.][t][.] only after it has been consumed (reads are of
  // t+1 at iter t, writes of t at iter t, separated by barriers).
  float* enc = hout;

  k_encgemm<<<4096, 256, 0, stream>>>(x, Wfc, bfc, enc);
  k_scan<<<256, 256, 0, stream>>>(enc, h0, eps, Wih, Whh, bih, bhh, Wout, bout,
                                  xout, hout);
}

// Round 2
// 258.743 us; speedup vs baseline: 1.1517x; 1.1517x over previous
//
#include <hip/hip_runtime.h>

typedef __attribute__((ext_vector_type(4))) float  f32x4;
typedef __attribute__((ext_vector_type(4))) __bf16 bf16x4;
typedef __attribute__((ext_vector_type(8))) __bf16 bf16x8;

#define MFMA16 __builtin_amdgcn_mfma_f32_16x16x32_bf16
#define TINY_THR 4.8789098e-18f
#define XOUT_N ((size_t)4096 * 64 * 45)
#define GI_LD 196  // f32 row stride for gi LDS (196%32=4 -> 2-way, free)

// barrier that only drains LDS ops (no vmcnt(0) store/load drain)
__device__ __forceinline__ void bar_lds() {
  asm volatile("s_waitcnt lgkmcnt(0)\n\ts_barrier" ::: "memory");
}

// LDS planes: row-major, 64 bf16 cols (128 B rows), XOR-swizzled (G4).
__device__ __forceinline__ int swz_off(int row, int col) {
  return row * 128 + (((col) << 1) ^ ((row & 7) << 4));
}

// MFMA 16x16x32 bf16 A/B fragment: row/col = lane&15,
// k = half*16 + 4*(lane>>4) + j   (halves in reg pairs [0:1],[2:3]).
__device__ __forceinline__ bf16x8 read_frag(const __bf16* p, int row, int col) {
  const char* base = (const char*)p + row * 128;
  const int r7 = (row & 7) << 4;
  bf16x4 a = *(const bf16x4*)(base + (((col) << 1) ^ r7));
  bf16x4 b = *(const bf16x4*)(base + (((col + 16) << 1) ^ r7));
  bf16x8 r;
  r[0] = a[0]; r[1] = a[1]; r[2] = a[2]; r[3] = a[3];
  r[4] = b[0]; r[5] = b[1]; r[6] = b[2]; r[7] = b[3];
  return r;
}

__device__ __forceinline__ void split_bf16(float v, __bf16& h, __bf16& l) {
  h = (__bf16)v;
  l = (__bf16)(v - (float)h);
}

// ---------------------------------------------------------------------------
// Kernel 0: prepack W_fc1 into bf16 hi/lo planes, per-K-chunk row-major:
//   Wpk[(c*2+p)*4096 + o*64 + col],  c=k>>6, col=k&63.
// ---------------------------------------------------------------------------
__global__ void k_prepW(const float* __restrict__ Wfc, __bf16* __restrict__ Wpk) {
  const int idx = blockIdx.x * 256 + threadIdx.x;  // 32768 total
  const float v = Wfc[idx];
  __bf16 h, l; split_bf16(v, h, l);
  const int row = idx >> 9, k = idx & 511;
  const int c = k >> 6, col = k & 63;
  Wpk[(c * 2 + 0) * 4096 + row * 64 + col] = h;
  Wpk[(c * 2 + 1) * 4096 + row * 64 + col] = l;
}

// ---------------------------------------------------------------------------
// Kernel 1: enc[b][t][o] = relu(x[b][t][:] . W_fc1[o][:] + b_fc1[o]),  f32 out
// One block per batch row b. M=64 (t), N=64 (o), K=512, KC=64.
// bf16x3 split GEMM; W tiles copied pre-split from Wpk (no W split VALU).
// ---------------------------------------------------------------------------
__global__ __launch_bounds__(256, 4) void k_encgemm(
    const float* __restrict__ x, const __bf16* __restrict__ Wpk,
    const float* __restrict__ bfc, float* __restrict__ enc) {
  __shared__ __bf16 xs[2][64 * 64];   // [plane][t row][k col]
  __shared__ __bf16 wsm[2][64 * 64];  // [plane][o row][k col]

  const int tid  = threadIdx.x;
  const int lane = tid & 63;
  const int wv   = tid >> 6;   // wave = M-tile
  const int fr   = lane & 15;
  const int q    = lane >> 4;
  const int b    = blockIdx.x;

  const int srow = tid >> 2;         // staging row (t or o)
  const int scol = (tid & 3) << 4;   // staging col base (16 cols)
  const float* xp = x + ((size_t)b * 64 + srow) * 512 + scol;

  f32x4 acc[4];
  #pragma unroll
  for (int nt = 0; nt < 4; ++nt) acc[nt] = (f32x4){0.f, 0.f, 0.f, 0.f};

  for (int c = 0; c < 8; ++c) {
    #pragma unroll
    for (int i = 0; i < 4; ++i) {
      f32x4 vx = *(const f32x4*)(xp + c * 64 + i * 4);
      bf16x4 xh, xl;
      #pragma unroll
      for (int j = 0; j < 4; ++j) {
        __bf16 h, l;
        split_bf16(vx[j], h, l); xh[j] = h; xl[j] = l;
      }
      const int off = swz_off(srow, scol + i * 4);
      *(bf16x4*)((char*)xs[0] + off) = xh;
      *(bf16x4*)((char*)xs[1] + off) = xl;
    }
    #pragma unroll
    for (int p = 0; p < 2; ++p) {
      const __bf16* src = Wpk + ((c * 2 + p) << 12) + srow * 64 + scol;
      bf16x8 v0 = *(const bf16x8*)(src);
      bf16x8 v1 = *(const bf16x8*)(src + 8);
      *(bf16x8*)((char*)wsm[p] + swz_off(srow, scol))     = v0;
      *(bf16x8*)((char*)wsm[p] + swz_off(srow, scol + 8)) = v1;
    }
    bar_lds();
    const int arow = wv * 16 + fr;
    bf16x8 Ah[2], Al[2];
    #pragma unroll
    for (int kk = 0; kk < 2; ++kk) {
      Ah[kk] = read_frag(xs[0], arow, kk * 32 + q * 4);
      Al[kk] = read_frag(xs[1], arow, kk * 32 + q * 4);
    }
    #pragma unroll
    for (int nt = 0; nt < 4; ++nt) {
      const int brow = nt * 16 + fr;
      #pragma unroll
      for (int kk = 0; kk < 2; ++kk) {
        bf16x8 Bh = read_frag(wsm[0], brow, kk * 32 + q * 4);
        bf16x8 Bl = read_frag(wsm[1], brow, kk * 32 + q * 4);
        acc[nt] = MFMA16(Ah[kk], Bh, acc[nt], 0, 0, 0);
        acc[nt] = MFMA16(Ah[kk], Bl, acc[nt], 0, 0, 0);
        acc[nt] = MFMA16(Al[kk], Bh, acc[nt], 0, 0, 0);
      }
    }
    bar_lds();
  }
  // epilogue: D row = t = wv*16 + 4q + e, col = o = nt*16 + fr
  #pragma unroll
  for (int nt = 0; nt < 4; ++nt) {
    const int o = nt * 16 + fr;
    const float bb = bfc[o];
    #pragma unroll
    for (int e = 0; e < 4; ++e) {
      const int t = wv * 16 + q * 4 + e;
      float v = acc[nt][e] + bb;
      enc[((size_t)b * 64 + t) * 64 + o] = fmaxf(v, 0.f);
    }
  }
}

// ---------------------------------------------------------------------------
// Kernel 2: fused GRU scan, producer/consumer wave split.
// 512 threads: waves 0-3 ("B") = serial path: gh = h.W_hh^T (18 MFMA) + gates.
// waves 4-7 ("A") = parallel path: gi[t+1] = enc[t+1].W_ih^T (18 MFMA, biases
// folded), logits[t-1] (waves 4-6), enc prefetch/split, softmax+eps -> xout.
// Raw lgkm-only barriers; gi double-buffered in LDS (f32, stride 196).
// ---------------------------------------------------------------------------
__global__ __launch_bounds__(512, 2) void k_scan(
    const float* __restrict__ enc, const float* __restrict__ h0g,
    const float* __restrict__ eps, const float* __restrict__ Wih,
    const float* __restrict__ Whh, const float* __restrict__ bih,
    const float* __restrict__ bhh, const float* __restrict__ Wout,
    const float* __restrict__ bout, float* __restrict__ xout,
    float* __restrict__ hout) {
  // 48KB union: [wstage 2x24KB] aliased by [hp 4KB | epd 4KB | gi 24.5KB | lgt 3KB]
  __shared__ __attribute__((aligned(16))) char smem[49152];
  __bf16* const wst0 = (__bf16*)smem;
  __bf16* const wst1 = (__bf16*)(smem + 24576);
  __bf16* const hp0  = (__bf16*)smem;
  __bf16* const hp1  = (__bf16*)(smem + 2048);
  __bf16* const ep0  = (__bf16*)(smem + 4096);
  __bf16* const ep1  = (__bf16*)(smem + 6144);
  float* const gi    = (float*)(smem + 8192);    // [2][16][GI_LD]
  float* const lgt   = (float*)(smem + 33280);   // [16][48]

  const int tid  = threadIdx.x;
  const int lane = tid & 63;
  const int wv   = tid >> 6;      // 0..7
  const int fr   = lane & 15;
  const int q    = lane >> 4;
  const int bbase = blockIdx.x * 16;
  const bool isB = (wv < 4);
  const int aw  = wv - 4;         // group-A wave id (valid when !isB)
  const int at  = tid & 255;      // group-A thread id
  const int sb  = at >> 4;        // batch row for staging/softmax
  const int sub = at & 15;
  const int so  = sub << 2;

  // ---- per-thread scalar state ----
  float hreg[4] = {0.f, 0.f, 0.f, 0.f};
  float biasNh = 0.f;
  int hcol = 0;
  float bR_ = 0.f, bZ_ = 0.f, bN_ = 0.f, boutv = 0.f, epsv = 0.f;
  if (isB) {
    hcol = wv * 16 + fr;
    biasNh = bhh[128 + hcol];
    #pragma unroll
    for (int e = 0; e < 4; ++e)
      hreg[e] = h0g[(size_t)(bbase + q * 4 + e) * 64 + hcol];
  } else {
    const int gc = aw * 16 + fr;
    bR_ = bih[gc] + bhh[gc];
    bZ_ = bih[64 + gc] + bhh[64 + gc];
    bN_ = bih[128 + gc];
    if (aw < 3 && gc < 45) boutv = bout[gc];
    epsv = eps[bbase + sb];
  }

  // ---- stage + hoist weights (wstage aliased, freed after) ----
  bf16x8 Fih[3][2][2], Fhh[3][2][2], Fout[2][2];
  for (int idx = tid; idx < 192 * 64; idx += 512) {
    __bf16 h, l; split_bf16(Wih[idx], h, l);
    const int off = swz_off(idx >> 6, idx & 63);
    *(__bf16*)((char*)wst0 + off) = h;
    *(__bf16*)((char*)wst1 + off) = l;
  }
  bar_lds();
  if (!isB) {
    #pragma unroll
    for (int t3 = 0; t3 < 3; ++t3)
      #pragma unroll
      for (int kk = 0; kk < 2; ++kk) {
        const int row = (aw + 4 * t3) * 16 + fr;
        Fih[t3][kk][0] = read_frag(wst0, row, kk * 32 + q * 4);
        Fih[t3][kk][1] = read_frag(wst1, row, kk * 32 + q * 4);
      }
  }
  bar_lds();
  for (int idx = tid; idx < 192 * 64; idx += 512) {
    __bf16 h, l; split_bf16(Whh[idx], h, l);
    const int off = swz_off(idx >> 6, idx & 63);
    *(__bf16*)((char*)wst0 + off) = h;
    *(__bf16*)((char*)wst1 + off) = l;
  }
  bar_lds();
  if (isB) {
    #pragma unroll
    for (int t3 = 0; t3 < 3; ++t3)
      #pragma unroll
      for (int kk = 0; kk < 2; ++kk) {
        const int row = (wv + 4 * t3) * 16 + fr;
        Fhh[t3][kk][0] = read_frag(wst0, row, kk * 32 + q * 4);
        Fhh[t3][kk][1] = read_frag(wst1, row, kk * 32 + q * 4);
      }
  }
  bar_lds();
  for (int idx = tid; idx < 48 * 64; idx += 512) {
    float v = (idx < 45 * 64) ? Wout[idx] : 0.f;
    __bf16 h, l; split_bf16(v, h, l);
    const int off = swz_off(idx >> 6, idx & 63);
    *(__bf16*)((char*)wst0 + off) = h;
    *(__bf16*)((char*)wst1 + off) = l;
  }
  bar_lds();
  if (!isB && aw < 3) {
    #pragma unroll
    for (int kk = 0; kk < 2; ++kk) {
      const int row = aw * 16 + fr;
      Fout[kk][0] = read_frag(wst0, row, kk * 32 + q * 4);
      Fout[kk][1] = read_frag(wst1, row, kk * 32 + q * 4);
    }
  }
  bar_lds();  // wstage reads done -> smem reusable as hp/epd/gi/lgt

  // ---- init hp = h0 pairs, epd = enc[0] pairs ----
  if (isB) {
    #pragma unroll
    for (int e = 0; e < 4; ++e) {
      __bf16 h, l; split_bf16(hreg[e], h, l);
      const int off = swz_off(q * 4 + e, hcol);
      *(__bf16*)((char*)hp0 + off) = h;
      *(__bf16*)((char*)hp1 + off) = l;
    }
  } else {
    f32x4 e0v = *(const f32x4*)(enc + ((size_t)(bbase + sb) * 64 + 0) * 64 + so);
    bf16x4 h4, l4;
    #pragma unroll
    for (int j = 0; j < 4; ++j) { __bf16 h, l; split_bf16(e0v[j], h, l); h4[j] = h; l4[j] = l; }
    const int off = swz_off(sb, so);
    *(bf16x4*)((char*)ep0 + off) = h4;
    *(bf16x4*)((char*)ep1 + off) = l4;
  }
  bar_lds();

  auto do_gi = [&](float* gbuf) {
    bf16x8 Eh[2], El[2];
    #pragma unroll
    for (int kk = 0; kk < 2; ++kk) {
      Eh[kk] = read_frag(ep0, fr, kk * 32 + q * 4);
      El[kk] = read_frag(ep1, fr, kk * 32 + q * 4);
    }
    f32x4 g0 = (f32x4){0.f, 0.f, 0.f, 0.f}, g1 = g0, g2 = g0;
    #pragma unroll
    for (int kk = 0; kk < 2; ++kk) {
      g0 = MFMA16(Eh[kk], Fih[0][kk][0], g0, 0, 0, 0);
      g0 = MFMA16(Eh[kk], Fih[0][kk][1], g0, 0, 0, 0);
      g0 = MFMA16(El[kk], Fih[0][kk][0], g0, 0, 0, 0);
      g1 = MFMA16(Eh[kk], Fih[1][kk][0], g1, 0, 0, 0);
      g1 = MFMA16(Eh[kk], Fih[1][kk][1], g1, 0, 0, 0);
      g1 = MFMA16(El[kk], Fih[1][kk][0], g1, 0, 0, 0);
      g2 = MFMA16(Eh[kk], Fih[2][kk][0], g2, 0, 0, 0);
      g2 = MFMA16(Eh[kk], Fih[2][kk][1], g2, 0, 0, 0);
      g2 = MFMA16(El[kk], Fih[2][kk][0], g2, 0, 0, 0);
    }
    const int gc = aw * 16 + fr;
    #pragma unroll
    for (int e = 0; e < 4; ++e) {
      const int r = (q * 4 + e) * GI_LD;
      gbuf[r + gc]       = g0[e] + bR_;
      gbuf[r + 64 + gc]  = g1[e] + bZ_;
      gbuf[r + 128 + gc] = g2[e] + bN_;
    }
  };

  // ---- warm-up: gi[0] from epd=enc[0]; prefetch enc[1] ----
  f32x4 ev;
  if (!isB) {
    do_gi(gi);  // buffer 0
    ev = *(const f32x4*)(enc + ((size_t)(bbase + sb) * 64 + 1) * 64 + so);
  }
  bar_lds();
  if (!isB) {
    bf16x4 h4, l4;
    #pragma unroll
    for (int j = 0; j < 4; ++j) { __bf16 h, l; split_bf16(ev[j], h, l); h4[j] = h; l4[j] = l; }
    const int off = swz_off(sb, so);
    *(bf16x4*)((char*)ep0 + off) = h4;
    *(bf16x4*)((char*)ep1 + off) = l4;
  }
  bar_lds();

  int cur = 0;
  for (int t = 0; t <= 64; ++t) {
    // ---------------- phase 1 ----------------
    if (isB) {
      if (t < 64) {
        const float* gb = gi + cur * (16 * GI_LD);
        float giR[4], giZ[4], giN[4];
        #pragma unroll
        for (int e = 0; e < 4; ++e) {
          const int r = (q * 4 + e) * GI_LD;
          giR[e] = gb[r + hcol];
          giZ[e] = gb[r + 64 + hcol];
          giN[e] = gb[r + 128 + hcol];
        }
        bf16x8 Hh[2], Hl[2];
        #pragma unroll
        for (int kk = 0; kk < 2; ++kk) {
          Hh[kk] = read_frag(hp0, fr, kk * 32 + q * 4);
          Hl[kk] = read_frag(hp1, fr, kk * 32 + q * 4);
        }
        f32x4 aR = (f32x4){giR[0], giR[1], giR[2], giR[3]};
        f32x4 aZ = (f32x4){giZ[0], giZ[1], giZ[2], giZ[3]};
        f32x4 aN = (f32x4){0.f, 0.f, 0.f, 0.f};
        #pragma unroll
        for (int kk = 0; kk < 2; ++kk) {
          aR = MFMA16(Hh[kk], Fhh[0][kk][0], aR, 0, 0, 0);
          aR = MFMA16(Hh[kk], Fhh[0][kk][1], aR, 0, 0, 0);
          aR = MFMA16(Hl[kk], Fhh[0][kk][0], aR, 0, 0, 0);
          aZ = MFMA16(Hh[kk], Fhh[1][kk][0], aZ, 0, 0, 0);
          aZ = MFMA16(Hh[kk], Fhh[1][kk][1], aZ, 0, 0, 0);
          aZ = MFMA16(Hl[kk], Fhh[1][kk][0], aZ, 0, 0, 0);
          aN = MFMA16(Hh[kk], Fhh[2][kk][0], aN, 0, 0, 0);
          aN = MFMA16(Hh[kk], Fhh[2][kk][1], aN, 0, 0, 0);
          aN = MFMA16(Hl[kk], Fhh[2][kk][0], aN, 0, 0, 0);
        }
        #pragma unroll
        for (int e = 0; e < 4; ++e) {
          const float rr = 1.f / (1.f + __expf(-aR[e]));
          const float zz = 1.f / (1.f + __expf(-aZ[e]));
          const float npre = giN[e] + rr * (aN[e] + biasNh);
          const float nn = 2.f / (1.f + __expf(-2.f * npre)) - 1.f;
          const float hv = (1.f - zz) * nn + zz * hreg[e];
          hreg[e] = hv;
          hout[((size_t)(bbase + q * 4 + e) * 64 + t) * 64 + hcol] = hv;
        }
      }
    } else {
      if (t <= 61)
        ev = *(const f32x4*)(enc + ((size_t)(bbase + sb) * 64 + (t + 2)) * 64 + so);
      if (t <= 62) do_gi(gi + (cur ^ 1) * (16 * GI_LD));
      if (t >= 1 && aw < 3) {
        bf16x8 Hh[2], Hl[2];
        #pragma unroll
        for (int kk = 0; kk < 2; ++kk) {
          Hh[kk] = read_frag(hp0, fr, kk * 32 + q * 4);
          Hl[kk] = read_frag(hp1, fr, kk * 32 + q * 4);
        }
        f32x4 lacc = (f32x4){0.f, 0.f, 0.f, 0.f};
        #pragma unroll
        for (int kk = 0; kk < 2; ++kk) {
          lacc = MFMA16(Hh[kk], Fout[kk][0], lacc, 0, 0, 0);
          lacc = MFMA16(Hh[kk], Fout[kk][1], lacc, 0, 0, 0);
          lacc = MFMA16(Hl[kk], Fout[kk][0], lacc, 0, 0, 0);
        }
        #pragma unroll
        for (int e = 0; e < 4; ++e)
          lgt[(q * 4 + e) * 48 + aw * 16 + fr] = lacc[e] + boutv;
      }
    }
    bar_lds();
    // ---------------- phase 2 ----------------
    if (isB) {
      if (t < 64) {
        #pragma unroll
        for (int e = 0; e < 4; ++e) {
          __bf16 h, l; split_bf16(hreg[e], h, l);
          const int off = swz_off(q * 4 + e, hcol);
          *(__bf16*)((char*)hp0 + off) = h;
          *(__bf16*)((char*)hp1 + off) = l;
        }
      }
    } else {
      if (t <= 61) {
        bf16x4 h4, l4;
        #pragma unroll
        for (int j = 0; j < 4; ++j) { __bf16 h, l; split_bf16(ev[j], h, l); h4[j] = h; l4[j] = l; }
        const int off = swz_off(sb, so);
        *(bf16x4*)((char*)ep0 + off) = h4;
        *(bf16x4*)((char*)ep1 + off) = l4;
      }
      if (t >= 1) {
        const float e0 = __expf(lgt[sb * 48 + sub]);
        const float e1 = (sub + 16 < 45) ? __expf(lgt[sb * 48 + sub + 16]) : 0.f;
        const float e2 = (sub + 32 < 45) ? __expf(lgt[sb * 48 + sub + 32]) : 0.f;
        float s = e0 + e1 + e2;
        s += __shfl_xor(s, 1, 16);
        s += __shfl_xor(s, 2, 16);
        s += __shfl_xor(s, 4, 16);
        s += __shfl_xor(s, 8, 16);
        if (s <= TINY_THR) s = 1.f;
        const float sc  = (1.f - epsv) / s;
        const float bse = epsv * (1.f / 45.f);
        float* orow = xout + ((size_t)(bbase + sb) * 64 + (t - 1)) * 45;
        orow[sub] = bse + e0 * sc;
        if (sub + 16 < 45) orow[sub + 16] = bse + e1 * sc;
        if (sub + 32 < 45) orow[sub + 32] = bse + e2 * sc;
      }
    }
    bar_lds();
    cur ^= 1;
  }
}

extern "C" void kernel_launch(void* const* d_in, const int* in_sizes, int n_in,
                              void* d_out, int out_size, void* d_ws, size_t ws_size,
                              hipStream_t stream) {
  (void)in_sizes; (void)n_in; (void)out_size; (void)d_ws; (void)ws_size;
  const float* x    = (const float*)d_in[0];
  const float* h0   = (const float*)d_in[1];
  const float* eps  = (const float*)d_in[2];
  const float* Wfc  = (const float*)d_in[3];
  const float* bfc  = (const float*)d_in[4];
  const float* Wih  = (const float*)d_in[5];
  const float* Whh  = (const float*)d_in[6];
  const float* bih  = (const float*)d_in[7];
  const float* bhh  = (const float*)d_in[8];
  const float* Wout = (const float*)d_in[9];
  const float* bout = (const float*)d_in[10];

  float* xout = (float*)d_out;
  float* hout = xout + XOUT_N;
  // enc scratch aliases the h_out region: slot t is read (global) at iter t-2
  // and written at iter t, separated by >=2 barriers + register consumption.
  float* enc = hout;
  // Wpk scratch aliases the start of the xout region (128 KB); k_encgemm
  // consumes it fully before k_scan overwrites xout (stream-ordered).
  __bf16* Wpk = (__bf16*)d_out;

  k_prepW<<<128, 256, 0, stream>>>(Wfc, Wpk);
  k_encgemm<<<4096, 256, 0, stream>>>(x, Wpk, bfc, enc);
  k_scan<<<256, 512, 0, stream>>>(enc, h0, eps, Wih, Whh, bih, bhh, Wout, bout,
                                  xout, hout);
}

// Round 3
// 236.451 us; speedup vs baseline: 1.2602x; 1.0943x over previous
//
#include <hip/hip_runtime.h>

typedef __attribute__((ext_vector_type(4))) float  f32x4;
typedef __attribute__((ext_vector_type(4))) __bf16 bf16x4;
typedef __attribute__((ext_vector_type(8))) __bf16 bf16x8;

#define MFMA16 __builtin_amdgcn_mfma_f32_16x16x32_bf16
#define TINY_THR 4.8789098e-18f
#define XOUT_N ((size_t)4096 * 64 * 45)

__device__ __forceinline__ void bar_lds() {
  asm volatile("s_waitcnt lgkmcnt(0)\n\ts_barrier" ::: "memory");
}
__device__ __forceinline__ void split_bf16(float v, __bf16& h, __bf16& l) {
  h = (__bf16)v; l = (__bf16)(v - (float)h);
}
__device__ __forceinline__ void gll16(const void* g, void* l) {
  __builtin_amdgcn_global_load_lds(
      (const __attribute__((address_space(1))) void*)g,
      (__attribute__((address_space(3))) void*)l, 16, 0, 0);
}

// Packed+swizzled bf16 tile [rows][64 cols], 128 B/row, 8 blocks of 16 B.
// Block bid=(kk<<2)|q holds cols kk*32 + half*16 + q*4 + j at pos half*4+j,
// stored at blk = bid ^ (row&7)  (bank-spread; frag = ONE ds_read_b128).
__device__ __forceinline__ int pk_off(int row, int col) {
  const int kk = col >> 5, rem = col & 31;
  const int half = rem >> 4, qq = (rem >> 2) & 3, j = rem & 3;
  return row * 128 + ((((kk << 2) | qq) ^ (row & 7)) << 4) + half * 8 + j * 2;
}
__device__ __forceinline__ bf16x8 frag_pk(const char* base, int row, int kk, int qq) {
  return *(const bf16x8*)(base + row * 128 + ((((kk << 2) | qq) ^ (row & 7)) << 4));
}

// ---------------------------------------------------------------------------
// Kernel 0: prepack W_fc1 -> bf16 hi/lo planes, per-K-chunk, frag-packed and
// swizzled so that LINEAR 16B global_load_lds lands it ready for frag_pk.
// Layout: Wpk[c*8192 + p*4096 + row*64 + blk*8 + half*4 + j]
// ---------------------------------------------------------------------------
__global__ void k_prepW(const float* __restrict__ Wfc, __bf16* __restrict__ Wpk) {
  const int idx = blockIdx.x * 256 + threadIdx.x;  // 32768 total
  const float v = Wfc[idx];
  __bf16 h, l; split_bf16(v, h, l);
  const int row = idx >> 9, k = idx & 511;
  const int c = k >> 6, kl = k & 63;
  const int kk = kl >> 5, rem = kl & 31;
  const int half = rem >> 4, q = (rem >> 2) & 3, j = rem & 3;
  const int blk = ((kk << 2) | q) ^ (row & 7);
  const int pos = c * 8192 + row * 64 + blk * 8 + half * 4 + j;
  Wpk[pos] = h;
  Wpk[pos + 4096] = l;
}

// ---------------------------------------------------------------------------
// Kernel 1: enc = relu(x . W_fc1^T + b), one block per batch row.
// global_load_lds(16B) staging, double-buffered, counted vmcnt(8) pipeline.
// x staged as f32 with per-lane source swizzle (16 blocks/row, ^(row&15));
// split to bf16 hi/lo at frag-read time. W pre-split/packed from Wpk.
// ---------------------------------------------------------------------------
__global__ __launch_bounds__(256, 2) void k_encgemm(
    const float* __restrict__ x, const __bf16* __restrict__ Wpk,
    const float* __restrict__ bfc, float* __restrict__ enc) {
  __shared__ __attribute__((aligned(16))) char sm[65536];
  // xs buf: sm + buf*16384            [64 rows][16 x 16B blocks]
  // ws buf: sm + 32768 + buf*16384    [2 planes][64 rows][8 x 16B blocks]
  const int tid  = threadIdx.x;
  const int lane = tid & 63;
  const int wv   = tid >> 6;
  const int fr   = lane & 15;
  const int q    = lane >> 4;
  const int b    = blockIdx.x;

  auto stage = [&](int c, int buf) {
    char* xbase = sm + buf * 16384;
    char* wbase = sm + 32768 + buf * 16384;
    #pragma unroll
    for (int i = 0; i < 4; ++i) {
      const int B   = wv * 256 + i * 64 + lane;
      const int row = B >> 4, blk = B & 15;
      const int bp  = blk ^ (row & 15);
      const int colb = ((bp >> 3) << 5) | ((bp & 1) << 4) | (((bp >> 1) & 3) << 2);
      const float* src = x + ((size_t)b * 64 + row) * 512 + c * 64 + colb;
      gll16(src, xbase + wv * 4096 + i * 1024);
    }
    #pragma unroll
    for (int i = 0; i < 4; ++i) {
      const __bf16* srcw = Wpk + c * 8192 + wv * 2048 + i * 512 + lane * 8;
      gll16(srcw, wbase + wv * 4096 + i * 1024);
    }
  };

  f32x4 acc[4];
  #pragma unroll
  for (int nt = 0; nt < 4; ++nt) acc[nt] = (f32x4){0.f, 0.f, 0.f, 0.f};

  stage(0, 0);
  int buf = 0;
  for (int c = 0; c < 8; ++c) {
    if (c < 7) {
      stage(c + 1, buf ^ 1);
      asm volatile("s_waitcnt vmcnt(8)\n\ts_barrier" ::: "memory");
    } else {
      asm volatile("s_waitcnt vmcnt(0)\n\ts_barrier" ::: "memory");
    }
    const char* xbase = sm + buf * 16384;
    const char* wbase = sm + 32768 + buf * 16384;
    const int arow = wv * 16 + fr;
    bf16x8 Ah[2], Al[2];
    #pragma unroll
    for (int kk = 0; kk < 2; ++kk) {
      f32x4 u0 = *(const f32x4*)(xbase + arow * 256 + (((kk * 8 + q * 2 + 0) ^ (arow & 15)) << 4));
      f32x4 u1 = *(const f32x4*)(xbase + arow * 256 + (((kk * 8 + q * 2 + 1) ^ (arow & 15)) << 4));
      #pragma unroll
      for (int j = 0; j < 4; ++j) {
        __bf16 h, l;
        split_bf16(u0[j], h, l); Ah[kk][j] = h;     Al[kk][j] = l;
        split_bf16(u1[j], h, l); Ah[kk][4 + j] = h; Al[kk][4 + j] = l;
      }
    }
    #pragma unroll
    for (int nt = 0; nt < 4; ++nt) {
      const int brow = nt * 16 + fr;
      #pragma unroll
      for (int kk = 0; kk < 2; ++kk) {
        bf16x8 Bh = frag_pk(wbase, brow, kk, q);
        bf16x8 Bl = frag_pk(wbase + 8192, brow, kk, q);
        acc[nt] = MFMA16(Ah[kk], Bh, acc[nt], 0, 0, 0);
        acc[nt] = MFMA16(Ah[kk], Bl, acc[nt], 0, 0, 0);
        acc[nt] = MFMA16(Al[kk], Bh, acc[nt], 0, 0, 0);
      }
    }
    bar_lds();
    buf ^= 1;
  }
  #pragma unroll
  for (int nt = 0; nt < 4; ++nt) {
    const int o = nt * 16 + fr;
    const float bb = bfc[o];
    #pragma unroll
    for (int e = 0; e < 4; ++e) {
      const int t = wv * 16 + q * 4 + e;
      float v = acc[nt][e] + bb;
      enc[((size_t)b * 64 + t) * 64 + o] = fmaxf(v, 0.f);
    }
  }
}

// ---------------------------------------------------------------------------
// Kernel 2: fused GRU scan, producer/consumer wave split, ONE barrier/iter.
// All LDS state double-buffered: read [cur], write [cur^1]. Loop unrolled x2
// so cur is compile-time. enc prefetch depth = 2 iterations (evA/evB regs).
// smem map (bytes): hp [buf*4096 + pl*2048) 0..8192 | epd +8192 | gi f32x4
// slots {R,Z,N,pad} 16384 + buf*16640 (stride 260 f32/row) | lgt 49664+buf*3072
// wstage (init only) uses [0, 49152).
// ---------------------------------------------------------------------------
__global__ __launch_bounds__(512, 1) void k_scan(
    const float* __restrict__ enc, const float* __restrict__ h0g,
    const float* __restrict__ eps, const float* __restrict__ Wih,
    const float* __restrict__ Whh, const float* __restrict__ bih,
    const float* __restrict__ bhh, const float* __restrict__ Wout,
    const float* __restrict__ bout, float* __restrict__ xout,
    float* __restrict__ hout) {
  __shared__ __attribute__((aligned(16))) char sm[55808];
  char* const wst0 = sm;
  char* const wst1 = sm + 24576;

  const int tid  = threadIdx.x;
  const int lane = tid & 63;
  const int wv   = tid >> 6;
  const int fr   = lane & 15;
  const int q    = lane >> 4;
  const int bbase = blockIdx.x * 16;
  const bool isB = (wv < 4);
  const int aw  = wv - 4;
  const int at  = tid & 255;
  const int sb  = at >> 4;
  const int sub = at & 15;
  const int so  = sub << 2;

  float hreg[4] = {0.f, 0.f, 0.f, 0.f};
  float biasNh = 0.f;
  int hcol = 0;
  float bR_ = 0.f, bZ_ = 0.f, bN_ = 0.f, boutv = 0.f, epsv = 0.f;
  if (isB) {
    hcol = wv * 16 + fr;
    biasNh = bhh[128 + hcol];
    #pragma unroll
    for (int e = 0; e < 4; ++e)
      hreg[e] = h0g[(size_t)(bbase + q * 4 + e) * 64 + hcol];
  } else {
    const int gc = aw * 16 + fr;
    bR_ = bih[gc] + bhh[gc];
    bZ_ = bih[64 + gc] + bhh[64 + gc];
    bN_ = bih[128 + gc];
    if (aw < 3 && gc < 45) boutv = bout[gc];
    epsv = eps[bbase + sb];
  }

  // ---- stage + hoist weights ----
  bf16x8 Fih[3][2][2], Fhh[3][2][2], Fout[2][2];
  for (int idx = tid; idx < 192 * 64; idx += 512) {
    __bf16 h, l; split_bf16(Wih[idx], h, l);
    const int off = pk_off(idx >> 6, idx & 63);
    *(__bf16*)(wst0 + off) = h;
    *(__bf16*)(wst1 + off) = l;
  }
  bar_lds();
  if (!isB) {
    #pragma unroll
    for (int t3 = 0; t3 < 3; ++t3)
      #pragma unroll
      for (int kk = 0; kk < 2; ++kk) {
        const int row = (aw + 4 * t3) * 16 + fr;
        Fih[t3][kk][0] = frag_pk(wst0, row, kk, q);
        Fih[t3][kk][1] = frag_pk(wst1, row, kk, q);
      }
  }
  bar_lds();
  for (int idx = tid; idx < 192 * 64; idx += 512) {
    __bf16 h, l; split_bf16(Whh[idx], h, l);
    const int off = pk_off(idx >> 6, idx & 63);
    *(__bf16*)(wst0 + off) = h;
    *(__bf16*)(wst1 + off) = l;
  }
  bar_lds();
  if (isB) {
    #pragma unroll
    for (int t3 = 0; t3 < 3; ++t3)
      #pragma unroll
      for (int kk = 0; kk < 2; ++kk) {
        const int row = (wv + 4 * t3) * 16 + fr;
        Fhh[t3][kk][0] = frag_pk(wst0, row, kk, q);
        Fhh[t3][kk][1] = frag_pk(wst1, row, kk, q);
      }
  }
  bar_lds();
  for (int idx = tid; idx < 48 * 64; idx += 512) {
    float v = (idx < 45 * 64) ? Wout[idx] : 0.f;
    __bf16 h, l; split_bf16(v, h, l);
    const int off = pk_off(idx >> 6, idx & 63);
    *(__bf16*)(wst0 + off) = h;
    *(__bf16*)(wst1 + off) = l;
  }
  bar_lds();
  if (!isB && aw < 3) {
    #pragma unroll
    for (int kk = 0; kk < 2; ++kk) {
      const int row = aw * 16 + fr;
      Fout[kk][0] = frag_pk(wst0, row, kk, q);
      Fout[kk][1] = frag_pk(wst1, row, kk, q);
    }
  }
  bar_lds();  // wstage free -> runtime buffers live

  auto put_epd = [&](int dst, const f32x4& ev) {
    bf16x4 h4, l4;
    #pragma unroll
    for (int j = 0; j < 4; ++j) { __bf16 h, l; split_bf16(ev[j], h, l); h4[j] = h; l4[j] = l; }
    char* p0 = sm + 8192 + dst * 4096;
    const int off = pk_off(sb, so);
    *(bf16x4*)(p0 + off) = h4;
    *(bf16x4*)(p0 + 2048 + off) = l4;
  };
  auto do_gi = [&](int src, int dst) {
    const char* e0c = sm + 8192 + src * 4096;
    const char* e1c = e0c + 2048;
    bf16x8 Eh[2], El[2];
    #pragma unroll
    for (int kk = 0; kk < 2; ++kk) {
      Eh[kk] = frag_pk(e0c, fr, kk, q);
      El[kk] = frag_pk(e1c, fr, kk, q);
    }
    f32x4 g0 = (f32x4){0.f, 0.f, 0.f, 0.f}, g1 = g0, g2 = g0;
    #pragma unroll
    for (int kk = 0; kk < 2; ++kk) {
      g0 = MFMA16(Eh[kk], Fih[0][kk][0], g0, 0, 0, 0);
      g0 = MFMA16(Eh[kk], Fih[0][kk][1], g0, 0, 0, 0);
      g0 = MFMA16(El[kk], Fih[0][kk][0], g0, 0, 0, 0);
      g1 = MFMA16(Eh[kk], Fih[1][kk][0], g1, 0, 0, 0);
      g1 = MFMA16(Eh[kk], Fih[1][kk][1], g1, 0, 0, 0);
      g1 = MFMA16(El[kk], Fih[1][kk][0], g1, 0, 0, 0);
      g2 = MFMA16(Eh[kk], Fih[2][kk][0], g2, 0, 0, 0);
      g2 = MFMA16(Eh[kk], Fih[2][kk][1], g2, 0, 0, 0);
      g2 = MFMA16(El[kk], Fih[2][kk][0], g2, 0, 0, 0);
    }
    float* gw = (float*)(sm + 16384 + dst * 16640);
    const int gc = aw * 16 + fr;
    #pragma unroll
    for (int e = 0; e < 4; ++e) {
      f32x4 o = (f32x4){g0[e] + bR_, g1[e] + bZ_, g2[e] + bN_, 0.f};
      *(f32x4*)(gw + (q * 4 + e) * 260 + gc * 4) = o;
    }
  };

  // ---- warm-up ----
  f32x4 evA, evB;
  if (!isB) {
    const float* eb = enc + (size_t)(bbase + sb) * 64 * 64 + so;
    f32x4 e0v = *(const f32x4*)(eb);
    f32x4 e1v = *(const f32x4*)(eb + 64);
    evA = *(const f32x4*)(eb + 2 * 64);
    evB = *(const f32x4*)(eb + 3 * 64);
    put_epd(1, e0v);
    bar_lds();
    do_gi(1, 0);       // gi[0] for step 0
    put_epd(0, e1v);   // epd[0] = enc[1]
  } else {
    char* h0b = sm;
    char* h1b = sm + 2048;
    #pragma unroll
    for (int e = 0; e < 4; ++e) {
      __bf16 h, l; split_bf16(hreg[e], h, l);
      const int off = pk_off(q * 4 + e, hcol);
      *(__bf16*)(h0b + off) = h;
      *(__bf16*)(h1b + off) = l;
    }
    bar_lds();
  }
  bar_lds();

  auto body = [&](int t, int cur, f32x4& evC) {
    if (isB) {
      if (t <= 63) {
        const float* gr = (const float*)(sm + 16384 + cur * 16640);
        f32x4 gv[4];
        #pragma unroll
        for (int e = 0; e < 4; ++e)
          gv[e] = *(const f32x4*)(gr + (q * 4 + e) * 260 + hcol * 4);
        const char* hp0c = sm + cur * 4096;
        const char* hp1c = hp0c + 2048;
        bf16x8 Hh[2], Hl[2];
        #pragma unroll
        for (int kk = 0; kk < 2; ++kk) {
          Hh[kk] = frag_pk(hp0c, fr, kk, q);
          Hl[kk] = frag_pk(hp1c, fr, kk, q);
        }
        f32x4 aR = (f32x4){gv[0][0], gv[1][0], gv[2][0], gv[3][0]};
        f32x4 aZ = (f32x4){gv[0][1], gv[1][1], gv[2][1], gv[3][1]};
        f32x4 aN = (f32x4){0.f, 0.f, 0.f, 0.f};
        #pragma unroll
        for (int kk = 0; kk < 2; ++kk) {
          aR = MFMA16(Hh[kk], Fhh[0][kk][0], aR, 0, 0, 0);
          aR = MFMA16(Hh[kk], Fhh[0][kk][1], aR, 0, 0, 0);
          aR = MFMA16(Hl[kk], Fhh[0][kk][0], aR, 0, 0, 0);
          aZ = MFMA16(Hh[kk], Fhh[1][kk][0], aZ, 0, 0, 0);
          aZ = MFMA16(Hh[kk], Fhh[1][kk][1], aZ, 0, 0, 0);
          aZ = MFMA16(Hl[kk], Fhh[1][kk][0], aZ, 0, 0, 0);
          aN = MFMA16(Hh[kk], Fhh[2][kk][0], aN, 0, 0, 0);
          aN = MFMA16(Hh[kk], Fhh[2][kk][1], aN, 0, 0, 0);
          aN = MFMA16(Hl[kk], Fhh[2][kk][0], aN, 0, 0, 0);
        }
        char* n0 = sm + (cur ^ 1) * 4096;
        char* n1 = n0 + 2048;
        #pragma unroll
        for (int e = 0; e < 4; ++e) {
          const float rr = 1.f / (1.f + __expf(-aR[e]));
          const float zz = 1.f / (1.f + __expf(-aZ[e]));
          const float npre = gv[e][2] + rr * (aN[e] + biasNh);
          const float nn = 2.f / (1.f + __expf(-2.f * npre)) - 1.f;
          const float hv = (1.f - zz) * nn + zz * hreg[e];
          hreg[e] = hv;
          hout[((size_t)(bbase + q * 4 + e) * 64 + t) * 64 + hcol] = hv;
          __bf16 h, l; split_bf16(hv, h, l);
          const int off = pk_off(q * 4 + e, hcol);
          *(__bf16*)(n0 + off) = h;
          *(__bf16*)(n1 + off) = l;
        }
      }
    } else {
      if (t <= 62) do_gi(cur, cur ^ 1);
      if (t >= 1 && t <= 64 && aw < 3) {
        const char* hp0c = sm + cur * 4096;
        const char* hp1c = hp0c + 2048;
        bf16x8 Hh[2], Hl[2];
        #pragma unroll
        for (int kk = 0; kk < 2; ++kk) {
          Hh[kk] = frag_pk(hp0c, fr, kk, q);
          Hl[kk] = frag_pk(hp1c, fr, kk, q);
        }
        f32x4 lacc = (f32x4){0.f, 0.f, 0.f, 0.f};
        #pragma unroll
        for (int kk = 0; kk < 2; ++kk) {
          lacc = MFMA16(Hh[kk], Fout[kk][0], lacc, 0, 0, 0);
          lacc = MFMA16(Hh[kk], Fout[kk][1], lacc, 0, 0, 0);
          lacc = MFMA16(Hl[kk], Fout[kk][0], lacc, 0, 0, 0);
        }
        float* lg = (float*)(sm + 49664 + (cur ^ 1) * 3072);
        #pragma unroll
        for (int e = 0; e < 4; ++e)
          lg[(q * 4 + e) * 48 + aw * 16 + fr] = lacc[e] + boutv;
      }
      if (t <= 61) put_epd(cur ^ 1, evC);
      if (t <= 59)
        evC = *(const f32x4*)(enc + ((size_t)(bbase + sb) * 64 + (t + 4)) * 64 + so);
      if (t >= 2) {
        const float* lg = (const float*)(sm + 49664 + cur * 3072);
        const float e0 = __expf(lg[sb * 48 + sub]);
        const float e1 = (sub + 16 < 45) ? __expf(lg[sb * 48 + sub + 16]) : 0.f;
        const float e2 = (sub + 32 < 45) ? __expf(lg[sb * 48 + sub + 32]) : 0.f;
        float s = e0 + e1 + e2;
        s += __shfl_xor(s, 1, 16);
        s += __shfl_xor(s, 2, 16);
        s += __shfl_xor(s, 4, 16);
        s += __shfl_xor(s, 8, 16);
        if (s <= TINY_THR) s = 1.f;
        const float sc  = (1.f - epsv) / s;
        const float bse = epsv * (1.f / 45.f);
        float* orow = xout + ((size_t)(bbase + sb) * 64 + (t - 2)) * 45;
        orow[sub] = bse + e0 * sc;
        if (sub + 16 < 45) orow[sub + 16] = bse + e1 * sc;
        if (sub + 32 < 45) orow[sub + 32] = bse + e2 * sc;
      }
    }
    bar_lds();
  };

  for (int t2 = 0; t2 < 66; t2 += 2) {
    body(t2, 0, evA);
    body(t2 + 1, 1, evB);
  }
}

extern "C" void kernel_launch(void* const* d_in, const int* in_sizes, int n_in,
                              void* d_out, int out_size, void* d_ws, size_t ws_size,
                              hipStream_t stream) {
  (void)in_sizes; (void)n_in; (void)out_size; (void)d_ws; (void)ws_size;
  const float* x    = (const float*)d_in[0];
  const float* h0   = (const float*)d_in[1];
  const float* eps  = (const float*)d_in[2];
  const float* Wfc  = (const float*)d_in[3];
  const float* bfc  = (const float*)d_in[4];
  const float* Wih  = (const float*)d_in[5];
  const float* Whh  = (const float*)d_in[6];
  const float* bih  = (const float*)d_in[7];
  const float* bhh  = (const float*)d_in[8];
  const float* Wout = (const float*)d_in[9];
  const float* bout = (const float*)d_in[10];

  float* xout = (float*)d_out;
  float* hout = xout + XOUT_N;
  // enc aliases h_out: slot t is clobbered (hout write) at iter t, 4 iters
  // after its last global read (enc[t+4] prefetch at iter t).
  float* enc = hout;
  // Wpk (128 KB) aliases start of xout; fully consumed by k_encgemm before
  // k_scan writes xout (stream-ordered).
  __bf16* Wpk = (__bf16*)d_out;

  k_prepW<<<128, 256, 0, stream>>>(Wfc, Wpk);
  k_encgemm<<<4096, 256, 0, stream>>>(x, Wpk, bfc, enc);
  k_scan<<<256, 512, 0, stream>>>(enc, h0, eps, Wih, Whh, bih, bhh, Wout, bout,
                                  xout, hout);
}